// Round 5
// baseline (621.882 us; speedup 1.0000x reference)
//
#include <hip/hip_runtime.h>

typedef unsigned short ushort_t;
typedef unsigned int uint_t;
typedef __bf16 bf16x8 __attribute__((ext_vector_type(8)));
typedef float floatx4 __attribute__((ext_vector_type(4)));

#define T_TOK 1024
#define HID 2880
#define NH 64
#define KV 8
#define HD 64
#define INTER 2880
#define QKV_DIM 5120   // HD*(NH+2*KV)
#define O_DIM 4096     // NH*HD

typedef __attribute__((address_space(1))) const uint_t glb_u32;
typedef __attribute__((address_space(3))) uint_t lds_u32;

__device__ __forceinline__ float b2f(ushort_t u) {
    uint_t i = ((uint_t)u) << 16;
    return __builtin_bit_cast(float, i);
}
__device__ __forceinline__ ushort_t f2b(float f) {
    uint_t i = __builtin_bit_cast(uint_t, f);
    uint_t r = i + 0x7FFFu + ((i >> 16) & 1u);
    return (ushort_t)(r >> 16);
}
__device__ __forceinline__ uint4 ld16(const void* p) { uint4 v; __builtin_memcpy(&v, p, 16); return v; }
__device__ __forceinline__ void st16(void* p, uint4 v) { __builtin_memcpy(p, &v, 16); }
__device__ __forceinline__ float4 ld16f(const void* p) { float4 v; __builtin_memcpy(&v, p, 16); return v; }
__device__ __forceinline__ bf16x8 ldfrag(const void* p) { bf16x8 v; __builtin_memcpy(&v, p, 16); return v; }
// native bf16 casts -> v_cvt_pk_bf16_f32 (RNE, bit-identical to the f2b trick)
__device__ __forceinline__ void cvt8st(void* lds, float4 a, float4 b) {
    __bf16 o[8] = {(__bf16)a.x, (__bf16)a.y, (__bf16)a.z, (__bf16)a.w,
                   (__bf16)b.x, (__bf16)b.y, (__bf16)b.z, (__bf16)b.w};
    __builtin_memcpy(lds, o, 16);
}

// ---------------- RMSNorm: f32 in -> bf16 out ------------------------------
__global__ __launch_bounds__(256) void rmsnorm_f2b(
    const float* __restrict__ x, const float* __restrict__ scale,
    ushort_t* __restrict__ out)
{
    const int row = blockIdx.x;
    const int tid = threadIdx.x;
    const float* xr = x + (size_t)row * HID;
    float ss = 0.f;
    for (int i = tid; i < HID / 4; i += 256) {
        float4 v = ld16f(xr + i * 4);
        ss += v.x * v.x + v.y * v.y + v.z * v.z + v.w * v.w;
    }
    #pragma unroll
    for (int m = 32; m >= 1; m >>= 1) ss += __shfl_xor(ss, m, 64);
    __shared__ float red[4];
    if ((tid & 63) == 0) red[tid >> 6] = ss;
    __syncthreads();
    float rstd = rsqrtf((red[0] + red[1] + red[2] + red[3]) / (float)HID + 1e-5f);
    for (int i = tid; i < HID / 8; i += 256) {
        float4 a = ld16f(xr + i * 8);
        float4 b = ld16f(xr + i * 8 + 4);
        float4 sa = ld16f(scale + i * 8);
        float4 sb = ld16f(scale + i * 8 + 4);
        cvt8st(out + (size_t)row * HID + i * 8,
               make_float4(a.x * rstd * sa.x, a.y * rstd * sa.y, a.z * rstd * sa.z, a.w * rstd * sa.w),
               make_float4(b.x * rstd * sb.x, b.y * rstd * sb.y, b.z * rstd * sb.z, b.w * rstd * sb.w));
    }
}

// ---------------- GEMM: C[M,N] = A_bf16[M,K] @ B_f32[N,K]^T + bias ---------
// BM=128, BN=64, BK=32, 256 threads (2x2 waves, wave tile 64x32).
// ALL staging via global_load_lds (A bf16, B raw f32; B converted f32->bf16
// in registers AFTER ds_read). LDS = 32 KB -> 5 blocks/CU (the R4 lever:
// previous 48 KB capped residency at 2 blocks -> 900 GB/s weight stream).
// Single barrier per K-step: vmcnt(0) BEFORE s_barrier guarantees all
// waves' glds(k) landed before any wave reads; glds(k+1) after the barrier
// targets the buffer whose readers all finished before reaching barrier(k).
// XOR-swizzled LDS on both tiles via pre-swizzled glds sources; read-side
// bank mapping verified 2 lanes/bank (free on wave64).
// N-MAJOR tile order (B panel L2 sharing) + bijective XCD chunking.
// Optional split-K (gridDim.y==2): z=1 writes f32 partial to scratch.
__global__ __launch_bounds__(256, 5) void gemm_bt(
    const ushort_t* __restrict__ A, const float* __restrict__ B,
    const float* __restrict__ bias, const float* residual,
    void* C, int out_f32, float* __restrict__ scratch,
    int M, int N, int K)
{
    __shared__ ushort_t As[2][128 * 32];   // 2 x 8 KB, rows of 64B (32 bf16)
    __shared__ float    Bs[2][64 * 32];    // 2 x 8 KB, rows of 128B (32 f32)
    const int tid = threadIdx.x;
    const int lane = tid & 63, wave = tid >> 6;
    const int l15 = lane & 15, quad = lane >> 4;

    // XCD-aware bijective remap: XCD k owns a contiguous chunk of flats.
    const int nbm = M >> 7;
    int flat = (int)blockIdx.x;
    const int cpx = (int)gridDim.x >> 3;
    flat = (flat & 7) * cpx + (flat >> 3);
    // n-major decode: consecutive flats share the B panel (n0), vary m0.
    const int m0 = (flat % nbm) * 128;
    const int n0 = (flat / nbm) * 64;

    const int wm = (wave >> 1) * 64, wn = (wave & 1) * 32;

    // split-K bounds (by 32-wide K-steps; handles nk odd)
    const int z = (int)blockIdx.y;
    const int nk_all = K >> 5;
    const int nk0 = (nk_all + 1) >> 1;
    const int kbeg = (gridDim.y > 1 && z) ? (nk0 << 5) : 0;
    const int nk = (gridDim.y > 1) ? (z ? nk_all - nk0 : nk0) : nk_all;

    // A glds (2 instr/wave, 16 rows each): lane l -> row wave*32+q*16+(l>>2),
    // LDS slot l&3 (16B). Pre-swizzled global slot so LDS holds
    // As[r][s] = global slot s ^ (r&3) ^ ((r>>2)&3).
    const int arow = wave * 32 + (lane >> 2);              // + q*16
    const int asl = (lane & 3) ^ ((lane >> 2) & 3) ^ ((lane >> 4) & 3);
    const ushort_t* Abase = A + (size_t)(m0 + arow) * K + kbeg + asl * 8;

    // B glds (2 instr/wave, 8 rows each): lane l -> row wave*16+q*8+(l>>3),
    // LDS slot l&7 (16B). Pre-swizzled: Bs[r][s] = global slot s ^ (r&7).
    const int brow = wave * 16 + (lane >> 3);              // + q*8
    const int bsl = (lane & 7) ^ ((lane >> 3) & 7);
    const float* Bbase = B + (size_t)(n0 + brow) * K + kbeg + bsl * 4;

    // read-side swizzled slot components (independent of i/j -- see layout)
    const int ar_sl = (quad ^ (l15 & 3) ^ ((l15 >> 2) & 3)) * 8;   // ushort idx
    const int br_lo = ((2 * quad) ^ (l15 & 7)) * 4;                // float idx
    const int br_hi = ((2 * quad + 1) ^ (l15 & 7)) * 4;

    floatx4 acc[4][2] = {};

    // ---- prologue: stage K-step 0 into buffer 0
    #pragma unroll
    for (int q = 0; q < 2; q++) {
        __builtin_amdgcn_global_load_lds(
            (glb_u32*)(Abase + (size_t)(q * 16) * K),
            (lds_u32*)(&As[0][(wave * 32 + q * 16) * 32]), 16, 0, 0);
        __builtin_amdgcn_global_load_lds(
            (glb_u32*)(Bbase + (size_t)(q * 8) * K),
            (lds_u32*)(&Bs[0][(wave * 16 + q * 8) * 32]), 16, 0, 0);
    }

    int cur = 0;
    for (int kt = 0; kt < nk; ++kt) {
        // all of THIS wave's glds(kt) retired; barrier makes everyone's visible
        asm volatile("s_waitcnt vmcnt(0)" ::: "memory");
        __builtin_amdgcn_s_barrier();
        __builtin_amdgcn_sched_barrier(0);   // no ds_read hoisted above

        if (kt + 1 < nk) {
            const int k1 = (kt + 1) << 5;
            const int nxt = cur ^ 1;
            #pragma unroll
            for (int q = 0; q < 2; q++) {
                __builtin_amdgcn_global_load_lds(
                    (glb_u32*)(Abase + (size_t)(q * 16) * K + k1),
                    (lds_u32*)(&As[nxt][(wave * 32 + q * 16) * 32]), 16, 0, 0);
                __builtin_amdgcn_global_load_lds(
                    (glb_u32*)(Bbase + (size_t)(q * 8) * K + k1),
                    (lds_u32*)(&Bs[nxt][(wave * 16 + q * 8) * 32]), 16, 0, 0);
            }
        }

        // ---- compute on buffer cur (loads for nxt in flight, no end barrier)
        bf16x8 af[4], bfr[2];
        #pragma unroll
        for (int i = 0; i < 4; i++)
            af[i] = ldfrag(&As[cur][(wm + i * 16 + l15) * 32 + ar_sl]);
        #pragma unroll
        for (int j = 0; j < 2; j++) {
            const float* bp = &Bs[cur][(wn + j * 16 + l15) * 32];
            float4 lo = ld16f(bp + br_lo);
            float4 hi = ld16f(bp + br_hi);
            bf16x8 b;
            b[0] = (__bf16)lo.x; b[1] = (__bf16)lo.y;
            b[2] = (__bf16)lo.z; b[3] = (__bf16)lo.w;
            b[4] = (__bf16)hi.x; b[5] = (__bf16)hi.y;
            b[6] = (__bf16)hi.z; b[7] = (__bf16)hi.w;
            bfr[j] = b;
        }
        #pragma unroll
        for (int i = 0; i < 4; i++)
            #pragma unroll
            for (int j = 0; j < 2; j++)
                acc[i][j] = __builtin_amdgcn_mfma_f32_16x16x32_bf16(af[i], bfr[j], acc[i][j], 0, 0, 0);
        cur ^= 1;
    }

    // epilogue: C layout col=lane&15, row=quad*4+r
    if (gridDim.y > 1 && z) {
        #pragma unroll
        for (int i = 0; i < 4; i++) {
            int row = m0 + wm + i * 16 + quad * 4;
            #pragma unroll
            for (int j = 0; j < 2; j++) {
                int col = n0 + wn + j * 16 + l15;
                #pragma unroll
                for (int r = 0; r < 4; r++)
                    scratch[(size_t)(row + r) * N + col] = acc[i][j][r];
            }
        }
        return;
    }
    #pragma unroll
    for (int i = 0; i < 4; i++) {
        int row = m0 + wm + i * 16 + quad * 4;
        #pragma unroll
        for (int j = 0; j < 2; j++) {
            int col = n0 + wn + j * 16 + l15;
            float bv = bias[col];
            #pragma unroll
            for (int r = 0; r < 4; r++) {
                float v = acc[i][j][r] + bv;
                if (residual) v += residual[(size_t)(row + r) * N + col];
                if (out_f32) ((float*)C)[(size_t)(row + r) * N + col] = v;
                else ((ushort_t*)C)[(size_t)(row + r) * N + col] = f2b(v);
            }
        }
    }
}

// ---------------- split-K reduction: dst += src (f32, T*HID elems) ---------
__global__ __launch_bounds__(256) void add_inplace(
    float* __restrict__ dst, const float* __restrict__ src)
{
    int i = (blockIdx.x * 256 + threadIdx.x) * 4;
    float4 a = ld16f(dst + i);
    float4 b = ld16f(src + i);
    a.x += b.x; a.y += b.y; a.z += b.z; a.w += b.w;
    __builtin_memcpy(dst + i, &a, 16);
}

// ---------------- RoPE (YaRN-style NTK) on bf16 qkv ------------------------
__global__ __launch_bounds__(256) void rope_kernel(ushort_t* __restrict__ qkv)
{
    int idx = blockIdx.x * 256 + threadIdx.x;  // T*(NH+KV)*32
    int d = idx & 31;
    int rest = idx >> 5;
    int head = rest % (NH + KV);
    int tok = rest / (NH + KV);

    // constants folded: log2(150000)=17.194638
    // low = 8.092761, high = 17.397992, conc = 1.3465736
    float fd = (float)d;
    float freq = exp2f(fd * (17.194638f / 32.0f));
    float interpolation = 1.0f / (32.0f * freq);
    float extrapolation = 1.0f / freq;
    float ramp = (fd - 8.092761f) * (1.0f / (17.397992f - 8.092761f));
    ramp = fminf(fmaxf(ramp, 0.0f), 1.0f);
    float mask = 1.0f - ramp;
    float inv_freq = interpolation * (1.0f - mask) + extrapolation * mask;
    float ang = (float)tok * inv_freq;
    float s = sinf(ang) * 1.3465736f;
    float c = cosf(ang) * 1.3465736f;

    size_t base = (head < NH)
        ? (size_t)tok * QKV_DIM + head * HD
        : (size_t)tok * QKV_DIM + NH * HD + (head - NH) * HD;
    float x1 = b2f(qkv[base + d]);
    float x2 = b2f(qkv[base + 32 + d]);
    qkv[base + d]      = f2b(x1 * c - x2 * s);
    qkv[base + 32 + d] = f2b(x2 * c + x1 * s);
}

// ---------------- Flash attention: causal GQA, one (head, 64-row Q tile) ---
__global__ __launch_bounds__(256) void attn_kernel(
    const ushort_t* __restrict__ qkv, ushort_t* __restrict__ o)
{
    const int qt = blockIdx.x;   // 0..15
    const int h  = blockIdx.y;   // 0..63
    const int g  = h >> 3;       // kv head
    const int tid = threadIdx.x;
    const int lane = tid & 63, wave = tid >> 6;
    const int l15 = lane & 15, quad = lane >> 4;

    __shared__ ushort_t Ks[64 * 72];      // K rows, padded stride 72
    __shared__ ushort_t Vt[64 * 72];      // V transposed: Vt[d][s]
    __shared__ ushort_t Ps[4][16 * 72];   // wave-private P

    bf16x8 qf[2];
    const int qrow = qt * 64 + wave * 16 + l15;
    #pragma unroll
    for (int c = 0; c < 2; c++)
        qf[c] = ldfrag(&qkv[(size_t)qrow * QKV_DIM + h * HD + quad * 8 + 32 * c]);

    floatx4 ofrag[4] = {};
    float mrow[4], lrow[4];
    #pragma unroll
    for (int r = 0; r < 4; r++) { mrow[r] = -1e30f; lrow[r] = 0.f; }

    for (int kt = 0; kt <= qt; ++kt) {
        {   // stage K (row-major, padded) and V (transposed)
            int row = tid >> 2;
            int seg = (tid & 3) * 16;
            size_t sb = (size_t)(kt * 64 + row) * QKV_DIM + NH * HD + g * HD;
            st16(&Ks[row * 72 + seg],     ld16(&qkv[sb + seg]));
            st16(&Ks[row * 72 + seg + 8], ld16(&qkv[sb + seg + 8]));
            uint4 v0 = ld16(&qkv[sb + KV * HD + seg]);
            uint4 v1 = ld16(&qkv[sb + KV * HD + seg + 8]);
            uint_t w0[4] = {v0.x, v0.y, v0.z, v0.w};
            uint_t w1[4] = {v1.x, v1.y, v1.z, v1.w};
            #pragma unroll
            for (int e = 0; e < 8; e++) {
                ushort_t s0 = (e & 1) ? (ushort_t)(w0[e >> 1] >> 16) : (ushort_t)(w0[e >> 1] & 0xffffu);
                ushort_t s1 = (e & 1) ? (ushort_t)(w1[e >> 1] >> 16) : (ushort_t)(w1[e >> 1] & 0xffffu);
                Vt[(seg + e) * 72 + row]     = s0;
                Vt[(seg + 8 + e) * 72 + row] = s1;
            }
        }
        __syncthreads();

        // S = Q K^T (scaled); C layout row=quad*4+r (query), col=lane&15 (key)
        floatx4 sf[4];
        #pragma unroll
        for (int j = 0; j < 4; j++) {
            floatx4 z = {};
            #pragma unroll
            for (int c = 0; c < 2; c++) {
                bf16x8 kf = ldfrag(&Ks[(j * 16 + l15) * 72 + quad * 8 + 32 * c]);
                z = __builtin_amdgcn_mfma_f32_16x16x32_bf16(qf[c], kf, z, 0, 0, 0);
            }
            sf[j] = z;
        }
        const int qg = qt * 64 + wave * 16 + quad * 4;
        const int kgb = kt * 64 + l15;
        float rowmax[4];
        #pragma unroll
        for (int r = 0; r < 4; r++) rowmax[r] = -1e30f;
        #pragma unroll
        for (int j = 0; j < 4; j++)
            #pragma unroll
            for (int r = 0; r < 4; r++) {
                float v = sf[j][r] * 0.125f;
                if (kgb + j * 16 > qg + r) v = -1e30f;
                sf[j][r] = v;
                rowmax[r] = fmaxf(rowmax[r], v);
            }
        #pragma unroll
        for (int r = 0; r < 4; r++)
            #pragma unroll
            for (int m = 1; m < 16; m <<= 1)
                rowmax[r] = fmaxf(rowmax[r], __shfl_xor(rowmax[r], m, 64));
        float alpha[4], rowsum[4];
        #pragma unroll
        for (int r = 0; r < 4; r++) {
            float mnew = fmaxf(mrow[r], rowmax[r]);
            alpha[r] = __expf(mrow[r] - mnew);
            mrow[r] = mnew;
            rowsum[r] = 0.f;
        }
        #pragma unroll
        for (int j = 0; j < 4; j++)
            #pragma unroll
            for (int r = 0; r < 4; r++) {
                float p = __expf(sf[j][r] - mrow[r]);
                rowsum[r] += p;
                Ps[wave][(quad * 4 + r) * 72 + j * 16 + l15] = f2b(p);
            }
        #pragma unroll
        for (int r = 0; r < 4; r++) {
            #pragma unroll
            for (int m = 1; m < 16; m <<= 1)
                rowsum[r] += __shfl_xor(rowsum[r], m, 64);
            lrow[r] = lrow[r] * alpha[r] + rowsum[r];
        }
        #pragma unroll
        for (int j = 0; j < 4; j++)
            #pragma unroll
            for (int r = 0; r < 4; r++)
                ofrag[j][r] *= alpha[r];
        __syncthreads();   // Ps visible before A-layout reads
        #pragma unroll
        for (int c = 0; c < 2; c++) {
            bf16x8 pf = ldfrag(&Ps[wave][l15 * 72 + quad * 8 + 32 * c]);
            #pragma unroll
            for (int j = 0; j < 4; j++) {
                bf16x8 vf = ldfrag(&Vt[(j * 16 + l15) * 72 + quad * 8 + 32 * c]);
                ofrag[j] = __builtin_amdgcn_mfma_f32_16x16x32_bf16(pf, vf, ofrag[j], 0, 0, 0);
            }
        }
        __syncthreads();
    }
    #pragma unroll
    for (int j = 0; j < 4; j++)
        #pragma unroll
        for (int r = 0; r < 4; r++) {
            int row = qt * 64 + wave * 16 + quad * 4 + r;
            int col = h * HD + j * 16 + l15;
            o[(size_t)row * O_DIM + col] = f2b(ofrag[j][r] / lrow[r]);
        }
}

// ---------------- gated activation: u bf16 [T,2I] -> ac bf16 [T,I] ---------
__global__ __launch_bounds__(256) void act_kernel(
    const ushort_t* __restrict__ u, ushort_t* __restrict__ act)
{
    int i = blockIdx.x * 256 + threadIdx.x;
    if (i >= T_TOK * INTER) return;
    int row = i / INTER, c = i % INTER;
    uint_t v; __builtin_memcpy(&v, u + (size_t)row * (2 * INTER) + 2 * c, 4);
    float gt  = b2f((ushort_t)(v & 0xffffu));
    float lin = b2f((ushort_t)(v >> 16));
    gt = fminf(gt, 7.0f);
    lin = fminf(fmaxf(lin, -7.0f), 7.0f);
    float sg = 1.0f / (1.0f + __expf(-1.702f * gt));
    act[i] = f2b(gt * sg * (lin + 1.0f));
}

extern "C" void kernel_launch(void* const* d_in, const int* in_sizes, int n_in,
                              void* d_out, int out_size, void* d_ws, size_t ws_size,
                              hipStream_t stream)
{
    const float* x               = (const float*)d_in[0];
    const float* attn_norm_scale = (const float*)d_in[1];
    const float* wqkv            = (const float*)d_in[2];
    const float* bqkv            = (const float*)d_in[3];
    const float* wout            = (const float*)d_in[4];
    const float* bout            = (const float*)d_in[5];
    const float* mlp_norm_scale  = (const float*)d_in[6];
    const float* w1              = (const float*)d_in[7];
    const float* b1              = (const float*)d_in[8];
    const float* w2              = (const float*)d_in[9];
    const float* b2              = (const float*)d_in[10];
    float* out = (float*)d_out;

    // ws (bf16 buffers, total 42.5 MB < proven 49.5):
    // [t 5.9][qkv 10.49][ob 8.39][u 11.8][ac 5.9]; h lives in d_out (f32).
    // Scratch reuse for split-K partials (f32, 11.8 MB = T*HID*4):
    //   wout partial -> u region (written by w1 only AFTER the reduce)
    //   w2 partial   -> qkv+ob region (dead after attn/wout)
    char* ws = (char*)d_ws;
    ushort_t* t   = (ushort_t*)ws;                               // T*HID
    ushort_t* qkv = (ushort_t*)(ws + (size_t)T_TOK * HID * 2);
    ushort_t* ob  = (ushort_t*)(ws + (size_t)T_TOK * (HID + QKV_DIM) * 2);
    ushort_t* u   = (ushort_t*)(ws + (size_t)T_TOK * (HID + QKV_DIM + O_DIM) * 2);
    ushort_t* ac  = (ushort_t*)(ws + (size_t)T_TOK * (HID + QKV_DIM + O_DIM + 2 * INTER) * 2);
    float* sc1 = (float*)u;      // wout split-K partial
    float* sc2 = (float*)qkv;    // w2 split-K partial

    rmsnorm_f2b<<<T_TOK, 256, 0, stream>>>(x, attn_norm_scale, t);
    gemm_bt<<<dim3((T_TOK / 128) * (QKV_DIM / 64)), 256, 0, stream>>>(
        t, wqkv, bqkv, nullptr, qkv, 0, nullptr, T_TOK, QKV_DIM, HID);
    rope_kernel<<<(T_TOK * (NH + KV) * 32) / 256, 256, 0, stream>>>(qkv);
    attn_kernel<<<dim3(T_TOK / 64, NH), 256, 0, stream>>>(qkv, ob);
    gemm_bt<<<dim3((T_TOK / 128) * (HID / 64), 2), 256, 0, stream>>>(
        ob, wout, bout, x, out, 1, sc1, T_TOK, HID, O_DIM);      // h -> d_out
    add_inplace<<<(T_TOK * HID) / 1024, 256, 0, stream>>>(out, sc1);
    rmsnorm_f2b<<<T_TOK, 256, 0, stream>>>(out, mlp_norm_scale, t);
    gemm_bt<<<dim3((T_TOK / 128) * ((2 * INTER) / 64)), 256, 0, stream>>>(
        t, w1, b1, nullptr, u, 0, nullptr, T_TOK, 2 * INTER, HID);
    act_kernel<<<(T_TOK * INTER + 255) / 256, 256, 0, stream>>>(u, ac);
    gemm_bt<<<dim3((T_TOK / 128) * (HID / 64), 2), 256, 0, stream>>>(
        ac, w2, b2, out, out, 1, sc2, T_TOK, HID, INTER);        // in-place residual
    add_inplace<<<(T_TOK * HID) / 1024, 256, 0, stream>>>(out, sc2);
}